// Round 3
// baseline (2104.362 us; speedup 1.0000x reference)
//
#include <hip/hip_runtime.h>
#include <hip/hip_bf16.h>

#define B_SZ  64
#define S_LEN 512
#define I_DIM 1024
#define H_DIM 1024

typedef __bf16 bf16x8 __attribute__((ext_vector_type(8)));
typedef __bf16 bf16x4 __attribute__((ext_vector_type(4)));
typedef float  f32x4  __attribute__((ext_vector_type(4)));
typedef unsigned u32x4 __attribute__((ext_vector_type(4)));

#define MFMA16(a,b,c) __builtin_amdgcn_mfma_f32_16x16x32_bf16((a),(b),(c),0,0,0)

__device__ inline bf16x8 cvt8(const float4& a, const float4& b) {
  bf16x8 v;
  v[0]=(__bf16)a.x; v[1]=(__bf16)a.y; v[2]=(__bf16)a.z; v[3]=(__bf16)a.w;
  v[4]=(__bf16)b.x; v[5]=(__bf16)b.y; v[6]=(__bf16)b.z; v[7]=(__bf16)b.w;
  return v;
}
__device__ inline bf16x8 cvt8v(const f32x4& a, const f32x4& b) {
  bf16x8 v;
  v[0]=(__bf16)a[0]; v[1]=(__bf16)a[1]; v[2]=(__bf16)a[2]; v[3]=(__bf16)a[3];
  v[4]=(__bf16)b[0]; v[5]=(__bf16)b[1]; v[6]=(__bf16)b[2]; v[7]=(__bf16)b[3];
  return v;
}

// ---- LLC-coherent (bypass L1/L2) helpers: cross-XCD data plane ----
__device__ inline u32x4 load_b128_sc(const void* p) {
  u32x4 r;
  asm volatile("global_load_dwordx4 %0, %1, off sc0 sc1"
               : "=v"(r) : "v"(p) : "memory");
  return r;
}
__device__ inline void store_b128_sc(void* p, u32x4 v) {
  asm volatile("global_store_dwordx4 %0, %1, off sc0 sc1"
               :: "v"(p), "v"(v) : "memory");
}
__device__ inline f32x4 load_b128_pf(const void* p) {   // normal cached load
  f32x4 r;
  asm volatile("global_load_dwordx4 %0, %1, off"
               : "=v"(r) : "v"(p) : "memory");
  return r;
}
__device__ inline void waitcnt_vm0() { asm volatile("s_waitcnt vmcnt(0)" ::: "memory"); }

// ---- phase 0: init chunk buffers ----
// chunk = 16B {bf16x4 h-data, u32 epoch tag, pad}. buf0: h(0), tag 0.
// buf1: tag 0xFFFFFFFF (never a valid epoch). Rewritten every launch ->
// replay-safe (no stale tags from a previous graph replay can match).
__global__ void k_hinit(const float* __restrict__ h0, u32x4* __restrict__ chunks) {
  const int ci = blockIdx.x * 256 + threadIdx.x;     // 16384 chunks/buffer
  const float4 v = ((const float4*)h0)[ci];
  bf16x4 hv;
  hv[0] = (__bf16)v.x; hv[1] = (__bf16)v.y; hv[2] = (__bf16)v.z; hv[3] = (__bf16)v.w;
  const unsigned long long h64 = __builtin_bit_cast(unsigned long long, hv);
  u32x4 pk;
  pk[0] = (unsigned)h64; pk[1] = (unsigned)(h64 >> 32); pk[2] = 0u; pk[3] = 0u;
  store_b128_sc(chunks + ci, pk);
  u32x4 inv;
  inv[0] = 0u; inv[1] = 0u; inv[2] = 0xFFFFFFFFu; inv[3] = 0u;
  store_b128_sc(chunks + 16384 + ci, inv);
}

// ---- phase 1: x_proj = seq @ w_ih^T + b_ih -> d_out (unchanged) ----
#define P1_LDA 40
__global__ __launch_bounds__(256, 2) void k_xproj(
    const float* __restrict__ A, const float* __restrict__ W,
    const float* __restrict__ bias, float* __restrict__ C) {
  constexpr int K = I_DIM, N = H_DIM;
  __shared__ __bf16 As[128][P1_LDA];
  __shared__ __bf16 Bs[128][P1_LDA];
  const int bid = blockIdx.x;
  const int nt = bid & 7, mt = bid >> 3;
  const int m0 = mt * 128, n0 = nt * 128;
  const int tid = threadIdx.x, lane = tid & 63, wv = tid >> 6;
  const int wm = (wv & 1) * 64, wn = (wv >> 1) * 64;
  const int fr = lane & 15, fq = lane >> 4;
  const int srow = tid >> 1, scol = (tid & 1) * 16;
  const float* gA = A + (size_t)(m0 + srow) * K + scol;
  const float* gB = W + (size_t)(n0 + srow) * K + scol;
  const f32x4 zero = {0.f, 0.f, 0.f, 0.f};
  f32x4 acc[4][4];
  #pragma unroll
  for (int m = 0; m < 4; ++m)
    #pragma unroll
    for (int n = 0; n < 4; ++n) acc[m][n] = zero;

  for (int k0 = 0; k0 < K; k0 += 32) {
    float4 a0 = *(const float4*)(gA + k0);
    float4 a1 = *(const float4*)(gA + k0 + 4);
    float4 a2 = *(const float4*)(gA + k0 + 8);
    float4 a3 = *(const float4*)(gA + k0 + 12);
    float4 b0 = *(const float4*)(gB + k0);
    float4 b1 = *(const float4*)(gB + k0 + 4);
    float4 b2 = *(const float4*)(gB + k0 + 8);
    float4 b3 = *(const float4*)(gB + k0 + 12);
    __syncthreads();
    *(bf16x8*)(&As[srow][scol])     = cvt8(a0, a1);
    *(bf16x8*)(&As[srow][scol + 8]) = cvt8(a2, a3);
    *(bf16x8*)(&Bs[srow][scol])     = cvt8(b0, b1);
    *(bf16x8*)(&Bs[srow][scol + 8]) = cvt8(b2, b3);
    __syncthreads();
    bf16x8 af[4], bfr[4];
    #pragma unroll
    for (int m = 0; m < 4; ++m) af[m]  = *(const bf16x8*)(&As[wm + m*16 + fr][fq*8]);
    #pragma unroll
    for (int n = 0; n < 4; ++n) bfr[n] = *(const bf16x8*)(&Bs[wn + n*16 + fr][fq*8]);
    #pragma unroll
    for (int m = 0; m < 4; ++m)
      #pragma unroll
      for (int n = 0; n < 4; ++n)
        acc[m][n] = MFMA16(af[m], bfr[n], acc[m][n]);
  }
  #pragma unroll
  for (int n = 0; n < 4; ++n) {
    const int col = n0 + wn + n*16 + fr;
    const float bv = bias[col];
    #pragma unroll
    for (int m = 0; m < 4; ++m) {
      const int row = m0 + wm + m*16 + fq*4;
      #pragma unroll
      for (int jj = 0; jj < 4; ++jj)
        C[(size_t)(row + jj) * N + col] = acc[m][n][jj] + bv;
    }
  }
}

// ---- phase 2: persistent recurrence, barrier-free (tag-in-data) ----
// 4 groups x 16 batches; 8 WGs/group x 512 thr (8 waves); WG owns 128 rows.
// W frags in VGPRs. h exchanged as 16B {data,tag} chunks at the LLC:
// consumers poll-load chunks and retire on tag==epoch. No atomic counter,
// no release drain on the critical path. Buffer parity (t&1) + monotone
// epoch gives ABA/lifetime safety (see chain argument in round notes).
#define NGR 4
#define BG  16
#define WPG 8
#define RPW 128
#define CPB (B_SZ * 256)          // chunks per buffer = 16384

__global__ __launch_bounds__(512, 1) void k_rnn(
    const float* __restrict__ w_hh, const float* __restrict__ b_hh,
    float* __restrict__ out, u32x4* __restrict__ chunks)
{
  __shared__ __bf16 Hs[BG][H_DIM];               // 32 KB, XOR-swizzled
  const int bid = blockIdx.x;
  const int g = bid >> 3, j = bid & 7;
  const int r0 = j * RPW;
  const int tid = threadIdx.x, lane = tid & 63, wv = tid >> 6;
  const int fr = lane & 15, fq = lane >> 4;
  const int myW  = r0 + wv * 16 + fr;            // A-frag W row
  const int row4 = r0 + wv * 16 + fq * 4;        // 4 consecutive output rows
  const int b    = g * BG + fr;                  // batch (D col)
  const int hswz = (fr & 7) << 3;

  // preload W fragments (loop-invariant): 32 x bf16x8
  bf16x8 wfrag[32];
  {
    const float* wsrc = w_hh + (size_t)myW * H_DIM + fq * 8;
    #pragma unroll
    for (int kk = 0; kk < 32; ++kk) {
      f32x4 w0 = *(const f32x4*)(wsrc + kk * 32);
      f32x4 w1 = *(const f32x4*)(wsrc + kk * 32 + 4);
      wfrag[kk] = cvt8v(w0, w1);
    }
  }
  const f32x4 bh = *(const f32x4*)(b_hh + row4);
  const size_t bsh = (size_t)B_SZ * S_LEN * H_DIM;
  const u32x4* gsrc0 = chunks + (size_t)g * (BG * 256);   // group base, buf0
  const size_t mysto = (size_t)b * 256 + (row4 >> 2);     // my chunk index

  size_t xo = (size_t)b * S_LEN * H_DIM + row4;
  f32x4 xv = load_b128_pf(out + xo);             // t=0 x prefetch

  for (int t = 0; t < S_LEN; ++t) {
    // ---- stage h_t: poll group's 4096 chunks, retire on tag match ----
    const u32x4* src = gsrc0 + (size_t)(t & 1) * CPB;
    unsigned pend = 0xFF;                        // 8 chunks/thread
    do {
      u32x4 st[8];
      #pragma unroll
      for (int i = 0; i < 8; ++i)
        if (pend & (1u << i)) st[i] = load_b128_sc(src + tid + (i << 9));
      waitcnt_vm0();
      #pragma unroll
      for (int i = 0; i < 8; ++i)
        if (pend & (1u << i)) {
          if (st[i][2] == (unsigned)t) {
            const int bb = (i << 1) + (tid >> 8); // chunk batch-in-group
            const int k4 = tid & 255;             // chunk k-quad
            const unsigned long long d =
                ((unsigned long long)st[i][1] << 32) | st[i][0];
            *(unsigned long long*)&Hs[bb][(k4 << 2) ^ ((bb & 7) << 3)] = d;
            pend &= ~(1u << i);
          }
        }
    } while (pend);
    __syncthreads();

    // ---- MFMA: 32 x 16x16x32, 4 acc chains ----
    const f32x4 z = {0.f, 0.f, 0.f, 0.f};
    f32x4 a0 = z, a1 = z, a2 = z, a3 = z;
    #pragma unroll
    for (int kk = 0; kk < 32; kk += 4) {
      bf16x8 h0 = *(const bf16x8*)&Hs[fr][((kk + 0) * 32 + fq * 8) ^ hswz];
      a0 = MFMA16(wfrag[kk + 0], h0, a0);
      bf16x8 h1 = *(const bf16x8*)&Hs[fr][((kk + 1) * 32 + fq * 8) ^ hswz];
      a1 = MFMA16(wfrag[kk + 1], h1, a1);
      bf16x8 h2 = *(const bf16x8*)&Hs[fr][((kk + 2) * 32 + fq * 8) ^ hswz];
      a2 = MFMA16(wfrag[kk + 2], h2, a2);
      bf16x8 h3 = *(const bf16x8*)&Hs[fr][((kk + 3) * 32 + fq * 8) ^ hswz];
      a3 = MFMA16(wfrag[kk + 3], h3, a3);
    }

    // ---- epilogue: v = relu(x + hW^T + b); publish {h,tag} in ONE store ----
    f32x4 s = (a0 + a1) + (a2 + a3);
    f32x4 r;
    r[0] = fmaxf(xv[0] + s[0] + bh[0], 0.f);
    r[1] = fmaxf(xv[1] + s[1] + bh[1], 0.f);
    r[2] = fmaxf(xv[2] + s[2] + bh[2], 0.f);
    r[3] = fmaxf(xv[3] + s[3] + bh[3], 0.f);
    *(f32x4*)(out + xo) = r;                     // overwrite x_t with h_t
    if (t == S_LEN - 1)
      *(f32x4*)(out + bsh + (size_t)b * H_DIM + row4) = r;  // h_last
    bf16x4 hv;
    hv[0] = (__bf16)r[0]; hv[1] = (__bf16)r[1];
    hv[2] = (__bf16)r[2]; hv[3] = (__bf16)r[3];
    const unsigned long long h64 = __builtin_bit_cast(unsigned long long, hv);
    u32x4 pk;
    pk[0] = (unsigned)h64; pk[1] = (unsigned)(h64 >> 32);
    pk[2] = (unsigned)(t + 1); pk[3] = 0u;
    store_b128_sc((void*)(chunks + (size_t)((t + 1) & 1) * CPB + mysto), pk);

    xo += H_DIM;
    xv = load_b128_pf(out + xo);                 // x_{t+1} prefetch
    __syncthreads();                             // Hs reuse guard
  }
}

extern "C" void kernel_launch(void* const* d_in, const int* in_sizes, int n_in,
                              void* d_out, int out_size, void* d_ws, size_t ws_size,
                              hipStream_t stream) {
  const float* seq  = (const float*)d_in[0];
  const float* h0   = (const float*)d_in[1];
  const float* w_ih = (const float*)d_in[2];
  const float* w_hh = (const float*)d_in[3];
  const float* b_ih = (const float*)d_in[4];
  const float* b_hh = (const float*)d_in[5];
  float* out = (float*)d_out;

  u32x4* chunks = (u32x4*)d_ws;                  // [2][B][H/4] x 16B = 512 KB

  k_hinit<<<dim3(CPB / 256), dim3(256), 0, stream>>>(h0, chunks);
  k_xproj<<<dim3((B_SZ * S_LEN / 128) * (H_DIM / 128)), dim3(256), 0, stream>>>(
      seq, w_ih, b_ih, out);

  const float* a0 = w_hh; const float* a1 = b_hh; float* a2 = out;
  u32x4* a3 = chunks;
  void* args[4] = { &a0, &a1, &a2, &a3 };
  hipLaunchCooperativeKernel((void*)k_rnn, dim3(NGR * WPG), dim3(512),
                             args, 0, stream);
}

// Round 5
// 1963.646 us; speedup vs baseline: 1.0717x; 1.0717x over previous
//
#include <hip/hip_runtime.h>
#include <hip/hip_bf16.h>

#define B_SZ  64
#define S_LEN 512
#define I_DIM 1024
#define H_DIM 1024
#define BH    (B_SZ * H_DIM)          // 65536 elems per h buffer

typedef __bf16 bf16x8 __attribute__((ext_vector_type(8)));
typedef __bf16 bf16x4 __attribute__((ext_vector_type(4)));
typedef float  f32x4  __attribute__((ext_vector_type(4)));
typedef unsigned u32x4 __attribute__((ext_vector_type(4)));

#define MFMA16(a,b,c) __builtin_amdgcn_mfma_f32_16x16x32_bf16((a),(b),(c),0,0,0)

__device__ inline bf16x8 cvt8(const float4& a, const float4& b) {
  bf16x8 v;
  v[0]=(__bf16)a.x; v[1]=(__bf16)a.y; v[2]=(__bf16)a.z; v[3]=(__bf16)a.w;
  v[4]=(__bf16)b.x; v[5]=(__bf16)b.y; v[6]=(__bf16)b.z; v[7]=(__bf16)b.w;
  return v;
}
__device__ inline bf16x8 cvt8v(const f32x4& a, const f32x4& b) {
  bf16x8 v;
  v[0]=(__bf16)a[0]; v[1]=(__bf16)a[1]; v[2]=(__bf16)a[2]; v[3]=(__bf16)a[3];
  v[4]=(__bf16)b[0]; v[5]=(__bf16)b[1]; v[6]=(__bf16)b[2]; v[7]=(__bf16)b[3];
  return v;
}

// ---- LLC-coherent (bypass L1/L2) helpers: cross-XCD data plane ----
__device__ inline u32x4 load_b128_sc(const void* p) {
  u32x4 r;
  asm volatile("global_load_dwordx4 %0, %1, off sc0 sc1"
               : "=v"(r) : "v"(p) : "memory");
  return r;
}
__device__ inline void st64_sc(void* p, unsigned long long v) {
  asm volatile("global_store_dwordx2 %0, %1, off sc0 sc1"
               :: "v"(p), "v"(v) : "memory");
}
__device__ inline f32x4 load_b128_pf(const void* p) {   // normal cached load
  f32x4 r;
  asm volatile("global_load_dwordx4 %0, %1, off"
               : "=v"(r) : "v"(p) : "memory");
  return r;
}
__device__ inline void waitcnt_vm0() {
  asm volatile("s_waitcnt vmcnt(0)" ::: "memory");
}

// ---- phase 0: h0 fp32 -> ht[0] bf16 (sc), zero 256 flags ----
__global__ void k_hinit(const float* __restrict__ h0, __bf16* __restrict__ ht,
                        unsigned* __restrict__ flags) {
  const int ci = blockIdx.x * 256 + threadIdx.x;   // 16384 f32x4 quads
  const float4 v = ((const float4*)h0)[ci];
  bf16x4 hv;
  hv[0] = (__bf16)v.x; hv[1] = (__bf16)v.y; hv[2] = (__bf16)v.z; hv[3] = (__bf16)v.w;
  st64_sc(ht + (size_t)ci * 4, __builtin_bit_cast(unsigned long long, hv));
  if (blockIdx.x == 0) {                           // 256 flag slots
    unsigned z = 0u;
    asm volatile("global_store_dword %0, %1, off sc0 sc1"
                 :: "v"(flags + threadIdx.x), "v"(z) : "memory");
  }
}

// ---- phase 1: x_proj = seq @ w_ih^T + b_ih -> d_out (unchanged, proven) ----
#define P1_LDA 40
__global__ __launch_bounds__(256, 2) void k_xproj(
    const float* __restrict__ A, const float* __restrict__ W,
    const float* __restrict__ bias, float* __restrict__ C) {
  constexpr int K = I_DIM, N = H_DIM;
  __shared__ __bf16 As[128][P1_LDA];
  __shared__ __bf16 Bs[128][P1_LDA];
  const int bid = blockIdx.x;
  const int nt = bid & 7, mt = bid >> 3;
  const int m0 = mt * 128, n0 = nt * 128;
  const int tid = threadIdx.x, lane = tid & 63, wv = tid >> 6;
  const int wm = (wv & 1) * 64, wn = (wv >> 1) * 64;
  const int fr = lane & 15, fq = lane >> 4;
  const int srow = tid >> 1, scol = (tid & 1) * 16;
  const float* gA = A + (size_t)(m0 + srow) * K + scol;
  const float* gB = W + (size_t)(n0 + srow) * K + scol;
  const f32x4 zero = {0.f, 0.f, 0.f, 0.f};
  f32x4 acc[4][4];
  #pragma unroll
  for (int m = 0; m < 4; ++m)
    #pragma unroll
    for (int n = 0; n < 4; ++n) acc[m][n] = zero;

  for (int k0 = 0; k0 < K; k0 += 32) {
    float4 a0 = *(const float4*)(gA + k0);
    float4 a1 = *(const float4*)(gA + k0 + 4);
    float4 a2 = *(const float4*)(gA + k0 + 8);
    float4 a3 = *(const float4*)(gA + k0 + 12);
    float4 b0 = *(const float4*)(gB + k0);
    float4 b1 = *(const float4*)(gB + k0 + 4);
    float4 b2 = *(const float4*)(gB + k0 + 8);
    float4 b3 = *(const float4*)(gB + k0 + 12);
    __syncthreads();
    *(bf16x8*)(&As[srow][scol])     = cvt8(a0, a1);
    *(bf16x8*)(&As[srow][scol + 8]) = cvt8(a2, a3);
    *(bf16x8*)(&Bs[srow][scol])     = cvt8(b0, b1);
    *(bf16x8*)(&Bs[srow][scol + 8]) = cvt8(b2, b3);
    __syncthreads();
    bf16x8 af[4], bfr[4];
    #pragma unroll
    for (int m = 0; m < 4; ++m) af[m]  = *(const bf16x8*)(&As[wm + m*16 + fr][fq*8]);
    #pragma unroll
    for (int n = 0; n < 4; ++n) bfr[n] = *(const bf16x8*)(&Bs[wn + n*16 + fr][fq*8]);
    #pragma unroll
    for (int m = 0; m < 4; ++m)
      #pragma unroll
      for (int n = 0; n < 4; ++n)
        acc[m][n] = MFMA16(af[m], bfr[n], acc[m][n]);
  }
  #pragma unroll
  for (int n = 0; n < 4; ++n) {
    const int col = n0 + wn + n*16 + fr;
    const float bv = bias[col];
    #pragma unroll
    for (int m = 0; m < 4; ++m) {
      const int row = m0 + wm + m*16 + fq*4;
      #pragma unroll
      for (int jj = 0; jj < 4; ++jj)
        C[(size_t)(row + jj) * N + col] = acc[m][n][jj] + bv;
    }
  }
}

// ---- phase 2: persistent recurrence (round-2/3 proven body, flag sync) ----
// 4 groups x 16 batches; 8 WGs/group x 512 thr (8 waves); WG owns 128 rows,
// wave owns 16. h ping-pongs through LLC (sc ops). Sync: per-wave flag
// (single writer) stored after the wave drains its own h-stores; consumers
// poll the group's 64 flags with one coalesced 64-lane sc load + __all.
// No atomics, no tid0 serialization. Lifetime: flag>=t+1 for all waves
// implies all h_t reads complete -> buffer (t&1) safe to overwrite at t+1.
#define NGR 4
#define BG  16
#define WPG 8

__global__ __launch_bounds__(512, 1) void k_rnn(
    const float* __restrict__ w_hh, const float* __restrict__ b_hh,
    float* __restrict__ out, __bf16* __restrict__ ht,
    unsigned* __restrict__ flags)
{
  __shared__ __bf16 Hs[BG][H_DIM];               // 32 KB, XOR-swizzled
  const int bid = blockIdx.x;
  const int g = bid >> 3, j = bid & 7;
  const int r0 = j * 128;
  const int tid = threadIdx.x, lane = tid & 63, wv = tid >> 6;
  const int fr = lane & 15, fq = lane >> 4;
  const int myW  = r0 + wv * 16 + fr;            // A-frag W row
  const int row4 = r0 + wv * 16 + fq * 4;        // 4 consecutive output rows
  const int b    = g * BG + fr;                  // batch (D col)
  const int hswz = (fr & 7) << 3;

  // W fragments: regular C++ loads; compiler keeps/rematerializes from L2
  // (proven path, rounds 2-3)
  bf16x8 wfrag[32];
  {
    const float* wsrc = w_hh + (size_t)myW * H_DIM + fq * 8;
    #pragma unroll
    for (int kk = 0; kk < 32; ++kk) {
      f32x4 w0 = *(const f32x4*)(wsrc + kk * 32);
      f32x4 w1 = *(const f32x4*)(wsrc + kk * 32 + 4);
      wfrag[kk] = cvt8v(w0, w1);
    }
  }
  const f32x4 bh = *(const f32x4*)(b_hh + row4);
  const size_t bsh = (size_t)B_SZ * S_LEN * H_DIM;
  const __bf16* hg0 = ht + (size_t)g * BG * H_DIM;     // group block, buf0
  const unsigned* fp = flags + (g << 6) + lane;        // poll addr (64 flags)
  unsigned* myfp = flags + (g << 6) + (j << 3) + wv;   // my flag slot

  size_t xo = (size_t)b * S_LEN * H_DIM + row4;
  f32x4 xv = load_b128_pf(out + xo);             // t=0 x prefetch

  for (int t = 0; t < S_LEN; ++t) {
    // ---- wait: all 64 waves of my group published h_t ----
    if (t) {
      const unsigned tt = (unsigned)t;
      for (;;) {
        unsigned f;
        asm volatile("global_load_dword %0, %1, off sc0 sc1"
                     : "=v"(f) : "v"(fp) : "memory");
        waitcnt_vm0();
        __builtin_amdgcn_sched_barrier(0);
        if (__all((int)(f >= tt))) break;
      }
    }

    // ---- stage h_t: LLC -> LDS (one-shot, 2048 x 16B chunks) ----
    const __bf16* hsrc = hg0 + (size_t)(t & 1) * BH;
    u32x4 st[4];
    #pragma unroll
    for (int i = 0; i < 4; ++i)
      st[i] = load_b128_sc(hsrc + (size_t)(tid + (i << 9)) * 8);
    waitcnt_vm0();
    __builtin_amdgcn_sched_barrier(0);
    #pragma unroll
    for (int i = 0; i < 4; ++i) {
      const int c = tid + (i << 9);
      const int bb = c >> 7, k = (c & 127) << 3;
      *(u32x4*)&Hs[bb][k ^ ((bb & 7) << 3)] = st[i];
    }
    __syncthreads();

    // ---- MFMA: 32 x 16x16x32, 4 acc chains (proven body) ----
    const f32x4 z = {0.f, 0.f, 0.f, 0.f};
    f32x4 a0 = z, a1 = z, a2 = z, a3 = z;
    #pragma unroll
    for (int kk = 0; kk < 32; kk += 4) {
      bf16x8 h0 = *(const bf16x8*)&Hs[fr][((kk + 0) * 32 + fq * 8) ^ hswz];
      a0 = MFMA16(wfrag[kk + 0], h0, a0);
      bf16x8 h1 = *(const bf16x8*)&Hs[fr][((kk + 1) * 32 + fq * 8) ^ hswz];
      a1 = MFMA16(wfrag[kk + 1], h1, a1);
      bf16x8 h2 = *(const bf16x8*)&Hs[fr][((kk + 2) * 32 + fq * 8) ^ hswz];
      a2 = MFMA16(wfrag[kk + 2], h2, a2);
      bf16x8 h3 = *(const bf16x8*)&Hs[fr][((kk + 3) * 32 + fq * 8) ^ hswz];
      a3 = MFMA16(wfrag[kk + 3], h3, a3);
    }

    // ---- epilogue: v = relu(x + hW^T + b) -> out, ht (sc), flag ----
    f32x4 s = (a0 + a1) + (a2 + a3);
    f32x4 r;
    r[0] = fmaxf(xv[0] + s[0] + bh[0], 0.f);
    r[1] = fmaxf(xv[1] + s[1] + bh[1], 0.f);
    r[2] = fmaxf(xv[2] + s[2] + bh[2], 0.f);
    r[3] = fmaxf(xv[3] + s[3] + bh[3], 0.f);
    *(f32x4*)(out + xo) = r;                     // overwrite x_t with h_t
    if (t == S_LEN - 1)
      *(f32x4*)(out + bsh + (size_t)b * H_DIM + row4) = r;  // h_last
    bf16x4 hv;
    hv[0] = (__bf16)r[0]; hv[1] = (__bf16)r[1];
    hv[2] = (__bf16)r[2]; hv[3] = (__bf16)r[3];
    __bf16* hd = ht + (size_t)((t + 1) & 1) * BH + (size_t)b * H_DIM + row4;
    st64_sc(hd, __builtin_bit_cast(unsigned long long, hv));

    waitcnt_vm0();                               // my wave's h at LLC
    if (lane == 0) {
      unsigned tv = (unsigned)(t + 1);
      asm volatile("global_store_dword %0, %1, off sc0 sc1"
                   :: "v"(myfp), "v"(tv) : "memory");
    }
    xo += H_DIM;
    xv = load_b128_pf(out + xo);                 // x_{t+1} prefetch
    __syncthreads();                             // Hs reuse guard
  }
}

extern "C" void kernel_launch(void* const* d_in, const int* in_sizes, int n_in,
                              void* d_out, int out_size, void* d_ws, size_t ws_size,
                              hipStream_t stream) {
  const float* seq  = (const float*)d_in[0];
  const float* h0   = (const float*)d_in[1];
  const float* w_ih = (const float*)d_in[2];
  const float* w_hh = (const float*)d_in[3];
  const float* b_ih = (const float*)d_in[4];
  const float* b_hh = (const float*)d_in[5];
  float* out = (float*)d_out;

  __bf16* ht = (__bf16*)d_ws;                               // [2][B][H] bf16
  unsigned* flags = (unsigned*)((char*)d_ws + (size_t)2 * BH * sizeof(__bf16));

  k_hinit<<<dim3(BH / 4 / 256), dim3(256), 0, stream>>>(h0, ht, flags);
  k_xproj<<<dim3((B_SZ * S_LEN / 128) * (H_DIM / 128)), dim3(256), 0, stream>>>(
      seq, w_ih, b_ih, out);

  const float* a0 = w_hh; const float* a1 = b_hh; float* a2 = out;
  __bf16* a3 = ht; unsigned* a4 = flags;
  void* args[5] = { &a0, &a1, &a2, &a3, &a4 };
  hipLaunchCooperativeKernel((void*)k_rnn, dim3(NGR * WPG), dim3(512),
                             args, 0, stream);
}

// Round 6
// 1836.905 us; speedup vs baseline: 1.1456x; 1.0690x over previous
//
#include <hip/hip_runtime.h>
#include <hip/hip_bf16.h>

#define B_SZ  64
#define S_LEN 512
#define I_DIM 1024
#define H_DIM 1024
#define BH    (B_SZ * H_DIM)          // 65536 elems per h buffer

typedef __bf16 bf16x8 __attribute__((ext_vector_type(8)));
typedef __bf16 bf16x4 __attribute__((ext_vector_type(4)));
typedef float  f32x4  __attribute__((ext_vector_type(4)));
typedef unsigned u32x4 __attribute__((ext_vector_type(4)));

#define MFMA16(a,b,c) __builtin_amdgcn_mfma_f32_16x16x32_bf16((a),(b),(c),0,0,0)

__device__ inline bf16x8 cvt8(const float4& a, const float4& b) {
  bf16x8 v;
  v[0]=(__bf16)a.x; v[1]=(__bf16)a.y; v[2]=(__bf16)a.z; v[3]=(__bf16)a.w;
  v[4]=(__bf16)b.x; v[5]=(__bf16)b.y; v[6]=(__bf16)b.z; v[7]=(__bf16)b.w;
  return v;
}

// ---- LLC-coherent (bypass L1/L2) helpers: cross-XCD data plane ----
__device__ inline u32x4 load_b128_sc(const void* p) {
  u32x4 r;
  asm volatile("global_load_dwordx4 %0, %1, off sc0 sc1"
               : "=v"(r) : "v"(p) : "memory");
  return r;
}
__device__ inline void st64_sc(void* p, unsigned long long v) {
  asm volatile("global_store_dwordx2 %0, %1, off sc0 sc1"
               :: "v"(p), "v"(v) : "memory");
}
__device__ inline f32x4 load_b128_pf(const void* p) {   // normal cached load
  f32x4 r;
  asm volatile("global_load_dwordx4 %0, %1, off"
               : "=v"(r) : "v"(p) : "memory");
  return r;
}
__device__ inline void waitcnt_vm0() {
  asm volatile("s_waitcnt vmcnt(0)" ::: "memory");
}

// ---- phase 0: h0 fp32 -> ht[0] bf16 (sc stores, proven round-5) ----
__global__ void k_hinit(const float* __restrict__ h0, __bf16* __restrict__ ht) {
  const int ci = blockIdx.x * 256 + threadIdx.x;   // 16384 f32x4 quads
  const float4 v = ((const float4*)h0)[ci];
  bf16x4 hv;
  hv[0] = (__bf16)v.x; hv[1] = (__bf16)v.y; hv[2] = (__bf16)v.z; hv[3] = (__bf16)v.w;
  st64_sc(ht + (size_t)ci * 4, __builtin_bit_cast(unsigned long long, hv));
}

// ---- phase 1: x_proj = seq @ w_ih^T + b_ih -> d_out (unchanged, proven) ----
#define P1_LDA 40
__global__ __launch_bounds__(256, 2) void k_xproj(
    const float* __restrict__ A, const float* __restrict__ W,
    const float* __restrict__ bias, float* __restrict__ C) {
  constexpr int K = I_DIM, N = H_DIM;
  __shared__ __bf16 As[128][P1_LDA];
  __shared__ __bf16 Bs[128][P1_LDA];
  const int bid = blockIdx.x;
  const int nt = bid & 7, mt = bid >> 3;
  const int m0 = mt * 128, n0 = nt * 128;
  const int tid = threadIdx.x, lane = tid & 63, wv = tid >> 6;
  const int wm = (wv & 1) * 64, wn = (wv >> 1) * 64;
  const int fr = lane & 15, fq = lane >> 4;
  const int srow = tid >> 1, scol = (tid & 1) * 16;
  const float* gA = A + (size_t)(m0 + srow) * K + scol;
  const float* gB = W + (size_t)(n0 + srow) * K + scol;
  const f32x4 zero = {0.f, 0.f, 0.f, 0.f};
  f32x4 acc[4][4];
  #pragma unroll
  for (int m = 0; m < 4; ++m)
    #pragma unroll
    for (int n = 0; n < 4; ++n) acc[m][n] = zero;

  for (int k0 = 0; k0 < K; k0 += 32) {
    float4 a0 = *(const float4*)(gA + k0);
    float4 a1 = *(const float4*)(gA + k0 + 4);
    float4 a2 = *(const float4*)(gA + k0 + 8);
    float4 a3 = *(const float4*)(gA + k0 + 12);
    float4 b0 = *(const float4*)(gB + k0);
    float4 b1 = *(const float4*)(gB + k0 + 4);
    float4 b2 = *(const float4*)(gB + k0 + 8);
    float4 b3 = *(const float4*)(gB + k0 + 12);
    __syncthreads();
    *(bf16x8*)(&As[srow][scol])     = cvt8(a0, a1);
    *(bf16x8*)(&As[srow][scol + 8]) = cvt8(a2, a3);
    *(bf16x8*)(&Bs[srow][scol])     = cvt8(b0, b1);
    *(bf16x8*)(&Bs[srow][scol + 8]) = cvt8(b2, b3);
    __syncthreads();
    bf16x8 af[4], bfr[4];
    #pragma unroll
    for (int m = 0; m < 4; ++m) af[m]  = *(const bf16x8*)(&As[wm + m*16 + fr][fq*8]);
    #pragma unroll
    for (int n = 0; n < 4; ++n) bfr[n] = *(const bf16x8*)(&Bs[wn + n*16 + fr][fq*8]);
    #pragma unroll
    for (int m = 0; m < 4; ++m)
      #pragma unroll
      for (int n = 0; n < 4; ++n)
        acc[m][n] = MFMA16(af[m], bfr[n], acc[m][n]);
  }
  #pragma unroll
  for (int n = 0; n < 4; ++n) {
    const int col = n0 + wn + n*16 + fr;
    const float bv = bias[col];
    #pragma unroll
    for (int m = 0; m < 4; ++m) {
      const int row = m0 + wm + m*16 + fq*4;
      #pragma unroll
      for (int jj = 0; jj < 4; ++jj)
        C[(size_t)(row + jj) * N + col] = acc[m][n][jj] + bv;
    }
  }
}

// ---- phase 2: persistent recurrence (round-2 structure, W in LDS) ----
// 4 groups x 16 batches; 16 WGs/group x 256 thr (4 waves); WG owns 64 rows.
// W: 128 KB LDS, XOR-swizzled, staged once (round-1-proven pattern) ->
// no per-step scratch/L2 W reloads (the round-2/3/5 hidden cost).
// h: 32 KB LDS panel staged per step from LLC (sc ops). Barrier: round-2
// proven monotone atomic counter (relaxed, post-drain).
#define NGR 4
#define BG  16
#define WPG 16
#define RPW 64

__global__ __launch_bounds__(256, 1) void k_rnn(
    const float* __restrict__ w_hh, const float* __restrict__ b_hh,
    float* __restrict__ out, __bf16* __restrict__ hbuf,
    unsigned* __restrict__ ctrs)
{
  __shared__ __bf16 Ws[RPW][H_DIM];              // 128 KB
  __shared__ __bf16 Hs[BG][H_DIM];               // 32 KB  (total 160 KB = CU max)
  const int bid = blockIdx.x;
  const int g = bid >> 4, j = bid & 15;
  const int r0 = j * RPW;
  const int tid = threadIdx.x, lane = tid & 63, wv = tid >> 6;
  const int fr = lane & 15, fq = lane >> 4;
  const int lr   = wv * 16 + fr;                 // local W row (0..63)
  const int row4 = r0 + wv * 16 + fq * 4;        // 4 consecutive output rows
  const int b    = g * BG + fr;                  // batch (D col)
  const int wswz = (fr & 7) << 3;
  const int hswz = (fr & 7) << 3;

  // ---- stage W slice once: 64 rows x 1024 fp32 -> bf16 swizzled LDS ----
  for (int idx = tid * 8; idx < RPW * H_DIM; idx += 256 * 8) {
    const int r = idx >> 10, k = idx & 1023;
    const float* src = w_hh + (size_t)(r0 + r) * H_DIM + k;
    float4 w0 = *(const float4*)(src);
    float4 w1 = *(const float4*)(src + 4);
    *(bf16x8*)(&Ws[r][k ^ ((r & 7) << 3)]) = cvt8(w0, w1);
  }
  __syncthreads();

  const f32x4 bh = *(const f32x4*)(b_hh + row4);
  unsigned* ctr = ctrs + (g << 6);               // 256 B apart per group
  const size_t bsh = (size_t)B_SZ * S_LEN * H_DIM;
  const __bf16* hg0 = hbuf + (size_t)g * BG * H_DIM;   // group block, buf0

  size_t xo = (size_t)b * S_LEN * H_DIM + row4;
  f32x4 xv = load_b128_pf(out + xo);             // t=0 x prefetch

  for (int t = 0; t < S_LEN; ++t) {
    // ---- stage h_t: LLC -> LDS (2048 x 16B chunks, swizzled ds_write) ----
    const __bf16* hsrc = hg0 + (size_t)(t & 1) * BH;
    u32x4 st[8];
    #pragma unroll
    for (int i = 0; i < 8; ++i) {
      const int c = tid + (i << 8);              // 2048 chunks
      st[i] = load_b128_sc(hsrc + (size_t)c * 8);
    }
    waitcnt_vm0();
    asm volatile("" : "+v"(xv));                 // pin: xv landed by now
    #pragma unroll
    for (int i = 0; i < 8; ++i) {
      const int c = tid + (i << 8);
      const int bb = c >> 7, k = (c & 127) << 3;
      *(u32x4*)&Hs[bb][k ^ ((bb & 7) << 3)] = st[i];
    }
    __syncthreads();

    // ---- MFMA: 32 x 16x16x32, 4 acc chains; A(W) and B(h) from LDS ----
    const f32x4 z = {0.f, 0.f, 0.f, 0.f};
    f32x4 a0 = z, a1 = z, a2 = z, a3 = z;
    #pragma unroll
    for (int kk = 0; kk < 32; kk += 4) {
      bf16x8 w0 = *(const bf16x8*)&Ws[lr][((kk + 0) * 32 + fq * 8) ^ wswz];
      bf16x8 h0 = *(const bf16x8*)&Hs[fr][((kk + 0) * 32 + fq * 8) ^ hswz];
      a0 = MFMA16(w0, h0, a0);
      bf16x8 w1 = *(const bf16x8*)&Ws[lr][((kk + 1) * 32 + fq * 8) ^ wswz];
      bf16x8 h1 = *(const bf16x8*)&Hs[fr][((kk + 1) * 32 + fq * 8) ^ hswz];
      a1 = MFMA16(w1, h1, a1);
      bf16x8 w2 = *(const bf16x8*)&Ws[lr][((kk + 2) * 32 + fq * 8) ^ wswz];
      bf16x8 h2 = *(const bf16x8*)&Hs[fr][((kk + 2) * 32 + fq * 8) ^ hswz];
      a2 = MFMA16(w2, h2, a2);
      bf16x8 w3 = *(const bf16x8*)&Ws[lr][((kk + 3) * 32 + fq * 8) ^ wswz];
      bf16x8 h3 = *(const bf16x8*)&Hs[fr][((kk + 3) * 32 + fq * 8) ^ hswz];
      a3 = MFMA16(w3, h3, a3);
    }

    // ---- epilogue: v = relu(x + hW^T + b) -> out, hbuf (sc) ----
    f32x4 s = (a0 + a1) + (a2 + a3);
    f32x4 r;
    r[0] = fmaxf(xv[0] + s[0] + bh[0], 0.f);
    r[1] = fmaxf(xv[1] + s[1] + bh[1], 0.f);
    r[2] = fmaxf(xv[2] + s[2] + bh[2], 0.f);
    r[3] = fmaxf(xv[3] + s[3] + bh[3], 0.f);
    *(f32x4*)(out + xo) = r;                     // overwrite x_t with h_t
    if (t == S_LEN - 1)
      *(f32x4*)(out + bsh + (size_t)b * H_DIM + row4) = r;  // h_last
    bf16x4 hv;
    hv[0] = (__bf16)r[0]; hv[1] = (__bf16)r[1];
    hv[2] = (__bf16)r[2]; hv[3] = (__bf16)r[3];
    __bf16* hd = hbuf + (size_t)((t + 1) & 1) * BH + (size_t)b * H_DIM + row4;
    st64_sc(hd, __builtin_bit_cast(unsigned long long, hv));

    // ---- barrier: drain, arrive, prefetch x_{t+1}, poll (round-2 proven) ----
    waitcnt_vm0();                               // h_{t+1} at LLC
    __syncthreads();                             // all waves drained
    if (tid == 0)
      __hip_atomic_fetch_add(ctr, 1u, __ATOMIC_RELAXED, __HIP_MEMORY_SCOPE_AGENT);
    xo += H_DIM;
    xv = load_b128_pf(out + xo);                 // overlaps with poll wait
    if (tid == 0) {
      const unsigned tgt = (unsigned)(t + 1) * WPG;
      while (__hip_atomic_load(ctr, __ATOMIC_RELAXED, __HIP_MEMORY_SCOPE_AGENT) < tgt)
        __builtin_amdgcn_s_sleep(1);
    }
    __syncthreads();
  }
}

extern "C" void kernel_launch(void* const* d_in, const int* in_sizes, int n_in,
                              void* d_out, int out_size, void* d_ws, size_t ws_size,
                              hipStream_t stream) {
  const float* seq  = (const float*)d_in[0];
  const float* h0   = (const float*)d_in[1];
  const float* w_ih = (const float*)d_in[2];
  const float* w_hh = (const float*)d_in[3];
  const float* b_ih = (const float*)d_in[4];
  const float* b_hh = (const float*)d_in[5];
  float* out = (float*)d_out;

  __bf16* hbuf = (__bf16*)d_ws;                  // [2][B][H] bf16 = 256 KB
  unsigned* ctrs = (unsigned*)((char*)d_ws + (size_t)2 * BH * sizeof(__bf16));

  hipMemsetAsync(ctrs, 0, NGR * 64 * sizeof(unsigned), stream);
  k_hinit<<<dim3(BH / 4 / 256), dim3(256), 0, stream>>>(h0, hbuf);
  k_xproj<<<dim3((B_SZ * S_LEN / 128) * (H_DIM / 128)), dim3(256), 0, stream>>>(
      seq, w_ih, b_ih, out);

  const float* a0 = w_hh; const float* a1 = b_hh; float* a2 = out;
  __bf16* a3 = hbuf; unsigned* a4 = ctrs;
  void* args[5] = { &a0, &a1, &a2, &a3, &a4 };
  hipLaunchCooperativeKernel((void*)k_rnn, dim3(NGR * WPG), dim3(256),
                             args, 0, stream);
}